// Round 8
// baseline (1287.407 us; speedup 1.0000x reference)
//
#include <hip/hip_runtime.h>
#include <hip/hip_bf16.h>
#include <hip/hip_cooperative_groups.h>
#include <cstdint>
#include <cstddef>

namespace cg = cooperative_groups;

// Problem: B=128, S=512, H=512, D=1024
// Outputs (flat in d_out): context (128*1024) | aw (128*512) | new_coverage (128*512)

typedef __attribute__((ext_vector_type(8))) short bf16x8;
typedef __attribute__((ext_vector_type(4))) float f32x4;

__device__ __forceinline__ short f2bf(float f) {
    union { float f; uint32_t u; } v; v.f = f;
    uint32_t u = v.u + 0x7fffu + ((v.u >> 16) & 1u);  // RNE
    return (short)(u >> 16);
}

__device__ __forceinline__ bf16x8 cvt8(float4 a, float4 b) {
    bf16x8 r;
    r[0] = f2bf(a.x); r[1] = f2bf(a.y); r[2] = f2bf(a.z); r[3] = f2bf(a.w);
    r[4] = f2bf(b.x); r[5] = f2bf(b.y); r[6] = f2bf(b.z); r[7] = f2bf(b.w);
    return r;
}

__device__ __forceinline__ float fast_tanh(float x) {
    x = fminf(10.f, fmaxf(-10.f, x));
    float e = __expf(2.f * x);
    return (e - 1.f) / (e + 1.f);
}

// ---------------- prep: Wh fp32->bf16 (blocks 0..1023) + dec split-K GEMM ------
__global__ __launch_bounds__(256) void prep_kernel(
    const float* __restrict__ Wh, short* __restrict__ Wh_bf,
    const float* __restrict__ hd, const float* __restrict__ cd,
    const float* __restrict__ Ws, float* __restrict__ dec_part)
{
    __shared__ __align__(16) short As[128 * 40];
    __shared__ __align__(16) short Bs[128 * 40];
    const int t = threadIdx.x;

    if (blockIdx.x < 1024) {
        int i = blockIdx.x * 1024 + t * 4;
        float4 f = *(const float4*)(Wh + i);
        short4 o;
        o.x = f2bf(f.x); o.y = f2bf(f.y); o.z = f2bf(f.z); o.w = f2bf(f.w);
        *(short4*)(Wh_bf + i) = o;
        return;
    }

    // ---- dec GEMM: M=128, N=1024, K split 4x256 ----
    const int bid = blockIdx.x - 1024;
    const int bx = bid & 7;        // n-tile 0..7
    const int kc = bid >> 3;       // k-chunk 0..3
    const int wv = t >> 6, lane = t & 63, q = lane >> 4, c = lane & 15;
    const int wm = wv & 1, wn = wv >> 1;
    const int ar = t >> 1, ah = t & 1;

    const float* abase = ((kc < 2) ? hd : cd) + (size_t)ar * 512 + (kc & 1) * 256 + ah * 16;
    const float* bbase = Ws + ((size_t)(bx * 128 + ar)) * 1024 + kc * 256 + ah * 16;
    short* awr = &As[ar * 40 + ah * 16];
    short* bwr = &Bs[ar * 40 + ah * 16];

    f32x4 acc[4][4];
#pragma unroll
    for (int i = 0; i < 4; ++i)
#pragma unroll
        for (int j = 0; j < 4; ++j) acc[i][j] = (f32x4){0.f, 0.f, 0.f, 0.f};

    for (int k0 = 0; k0 < 256; k0 += 32) {
        const float4* ap = (const float4*)(abase + k0);
        const float4* bp = (const float4*)(bbase + k0);
        float4 a0 = ap[0], a1 = ap[1], a2 = ap[2], a3 = ap[3];
        float4 b0 = bp[0], b1 = bp[1], b2 = bp[2], b3 = bp[3];
        *(bf16x8*)awr = cvt8(a0, a1);
        *(bf16x8*)(awr + 8) = cvt8(a2, a3);
        *(bf16x8*)bwr = cvt8(b0, b1);
        *(bf16x8*)(bwr + 8) = cvt8(b2, b3);
        __syncthreads();
        bf16x8 af[4], bf[4];
#pragma unroll
        for (int i = 0; i < 4; ++i) af[i] = *(const bf16x8*)&As[(wm * 64 + i * 16 + c) * 40 + q * 8];
#pragma unroll
        for (int j = 0; j < 4; ++j) bf[j] = *(const bf16x8*)&Bs[(wn * 64 + j * 16 + c) * 40 + q * 8];
#pragma unroll
        for (int i = 0; i < 4; ++i)
#pragma unroll
            for (int j = 0; j < 4; ++j)
                acc[i][j] = __builtin_amdgcn_mfma_f32_16x16x32_bf16(af[i], bf[j], acc[i][j], 0, 0, 0);
        __syncthreads();
    }

    const int n0 = bx * 128 + wn * 64;
    float* dp = dec_part + (size_t)kc * 131072;
#pragma unroll
    for (int i = 0; i < 4; ++i)
#pragma unroll
        for (int rr = 0; rr < 4; ++rr) {
            int bidx = wm * 64 + i * 16 + q * 4 + rr;
#pragma unroll
            for (int j = 0; j < 4; ++j)
                dp[(size_t)bidx * 1024 + n0 + j * 16 + c] = acc[i][j][rr];
        }
}

// ---------------- score GEMM: NO LDS, NO BARRIERS — direct fragment loads ------
// M=65536, N=1024, K=1024. Each wave loads A/B MFMA fragments straight from
// global (16 B/lane wave-gather matching the intrinsic layout). A is fp32 enc,
// cvt to bf16 in-register (no prepass). B is bf16 Wh (L2-hot, 2 MB). 1-iter
// register prefetch; latency hidden by waves/SIMD + MFMA/VALU co-issue.
__global__ __launch_bounds__(256) void attn_score_gemm7(
    const float* __restrict__ enc, const short* __restrict__ Whb,
    const float* __restrict__ dec_part, const float* __restrict__ Wsb,
    const float* __restrict__ cov, const float* __restrict__ wc_w,
    const float* __restrict__ v_w, float* __restrict__ p_part)
{
    const int t = threadIdx.x;
    const int lin = blockIdx.x;
    const int xcd = lin & 7;
    const int kk  = lin >> 3;
    const int bx  = kk & 7;                    // n-tile (fast within XCD -> L2 reuse of A)
    const int by  = xcd * 64 + (kk >> 3);      // m-tile 0..511
    const int b   = by >> 2;
    const int s0  = (by & 3) * 128;

    const int wv = t >> 6, lane = t & 63, q = lane >> 4, c = lane & 15;
    const int wm = wv & 1, wn = wv >> 1;

    const float* ap[4];
    const short* bp[4];
#pragma unroll
    for (int i = 0; i < 4; ++i)
        ap[i] = enc + ((size_t)(by * 128 + wm * 64 + i * 16 + c)) * 1024 + q * 8;
#pragma unroll
    for (int j = 0; j < 4; ++j)
        bp[j] = Whb + ((size_t)(bx * 128 + wn * 64 + j * 16 + c)) * 1024 + q * 8;

    f32x4 acc[4][4];
#pragma unroll
    for (int i = 0; i < 4; ++i)
#pragma unroll
        for (int j = 0; j < 4; ++j) acc[i][j] = (f32x4){0.f, 0.f, 0.f, 0.f};

    // prefetch k-tile 0
    float4 an0[4], an1[4];
    bf16x8 bn[4];
#pragma unroll
    for (int i = 0; i < 4; ++i) {
        an0[i] = *(const float4*)(ap[i]);
        an1[i] = *(const float4*)(ap[i] + 4);
    }
#pragma unroll
    for (int j = 0; j < 4; ++j) bn[j] = *(const bf16x8*)(bp[j]);

    for (int k0 = 0; k0 < 32; ++k0) {
        bf16x8 af[4], bf[4];
#pragma unroll
        for (int i = 0; i < 4; ++i) af[i] = cvt8(an0[i], an1[i]);
#pragma unroll
        for (int j = 0; j < 4; ++j) bf[j] = bn[j];
        if (k0 < 31) {
            const int kb = (k0 + 1) * 32;
#pragma unroll
            for (int i = 0; i < 4; ++i) {
                an0[i] = *(const float4*)(ap[i] + kb);
                an1[i] = *(const float4*)(ap[i] + kb + 4);
            }
#pragma unroll
            for (int j = 0; j < 4; ++j) bn[j] = *(const bf16x8*)(bp[j] + kb);
        }
#pragma unroll
        for (int i = 0; i < 4; ++i)
#pragma unroll
            for (int j = 0; j < 4; ++j)
                acc[i][j] = __builtin_amdgcn_mfma_f32_16x16x32_bf16(af[i], bf[j], acc[i][j], 0, 0, 0);
    }

    // Epilogue: p = sum_e v[e]*tanh(acc + dec[b,e] + cov[b,s]*wc[e])
    const int n0 = bx * 128 + wn * 64;
    float v_e[4], wc_e[4], dec_e[4];
#pragma unroll
    for (int j = 0; j < 4; ++j) {
        int e = n0 + j * 16 + c;
        v_e[j]  = v_w[e];
        wc_e[j] = wc_w[e];
        float d = Wsb[e];
#pragma unroll
        for (int p = 0; p < 4; ++p) d += dec_part[(size_t)p * 131072 + (size_t)b * 1024 + e];
        dec_e[j] = d;
    }
    const float* covb = cov + (size_t)b * 512;
    float* pp = p_part + ((size_t)(bx * 2 + wn)) * 65536 + (size_t)b * 512;
#pragma unroll
    for (int i = 0; i < 4; ++i)
#pragma unroll
        for (int rr = 0; rr < 4; ++rr) {
            int s = s0 + wm * 64 + i * 16 + q * 4 + rr;
            float cs = covb[s];
            float p = 0.f;
#pragma unroll
            for (int j = 0; j < 4; ++j) {
                float att = acc[i][j][rr] + dec_e[j] + cs * wc_e[j];
                p += v_e[j] * fast_tanh(att);
            }
            p += __shfl_xor(p, 1);
            p += __shfl_xor(p, 2);
            p += __shfl_xor(p, 4);
            p += __shfl_xor(p, 8);
            if (c == 0) pp[s] = p;
        }
}

// ---------------- cooperative post: softmax -> context -> reduce ---------------
// 256 blocks x 1024 threads (1 block/CU co-resident).
// FIX vs R7: only g==0 threads contribute to the renorm sum s2 (the duplicated
// per-s threads were double-counting the normalizer -> aw came out halved).
// Any uniform scaling of wvv (from the duplicated first denominator) cancels
// in wvv/s2, so this is correct by construction.
__global__ __launch_bounds__(1024) void post_kernel(
    const float* __restrict__ p_part, const float* __restrict__ mask,
    const float* __restrict__ cov, const float* __restrict__ enc,
    float* __restrict__ aw, float* __restrict__ ncov,
    float* __restrict__ ctx, float* __restrict__ cpart)
{
    cg::grid_group grid = cg::this_grid();
    __shared__ float sc2[2][512];
    __shared__ float red[16];
    __shared__ float racc[4][256][4];
    const int t = threadIdx.x;
    const int blk = blockIdx.x;
    const int w = t >> 6, lane = t & 63;

    // ---- phase 1: softmax + renorm + new_coverage (blocks 0..127) ----
    if (blk < 128) {
        const int b = blk, s = t & 511, g = t >> 9;
        float p = 0.f;
#pragma unroll
        for (int k = 0; k < 8; ++k)
            p += p_part[((size_t)(g * 8 + k) * 128 + b) * 512 + s];
        sc2[g][s] = p;
        __syncthreads();
        float sc = sc2[0][s] + sc2[1][s];
        const size_t idx = (size_t)b * 512 + s;

        float m = sc;
#pragma unroll
        for (int o = 1; o < 64; o <<= 1) m = fmaxf(m, __shfl_xor(m, o));
        if (lane == 0) red[w] = m;
        __syncthreads();
#pragma unroll
        for (int i = 0; i < 16; ++i) m = fmaxf(m, red[i]);
        __syncthreads();

        float e = __expf(sc - m);
        float ssum = e;                 // double-counted (uniform scale, cancels)
#pragma unroll
        for (int o = 1; o < 64; o <<= 1) ssum += __shfl_xor(ssum, o);
        if (lane == 0) red[w] = ssum;
        __syncthreads();
        ssum = 0.f;
#pragma unroll
        for (int i = 0; i < 16; ++i) ssum += red[i];
        __syncthreads();

        float wvv = (e / ssum) * mask[idx];
        float contrib = (g == 0) ? wvv : 0.f;   // each s counted exactly once
        float s2 = contrib;
#pragma unroll
        for (int o = 1; o < 64; o <<= 1) s2 += __shfl_xor(s2, o);
        if (lane == 0) red[w] = s2;
        __syncthreads();
        s2 = 0.f;
#pragma unroll
        for (int i = 0; i < 16; ++i) s2 += red[i];

        float awv = wvv / s2;
        if (g == 0) {
            aw[idx] = awv;
            ncov[idx] = cov[idx] + awv;
        }
    }
    __threadfence();
    grid.sync();

    // ---- phase 2: context partials (all 256 blocks) ----
    {
        const int b = blk >> 1, sh = blk & 1;
        const int dl = t & 255, sq = t >> 8;      // dl: d/4 index, sq: s-quarter
        const int d4 = dl * 4;
        const float* eb = enc + ((size_t)(b * 512 + sh * 256 + sq * 64)) * 1024 + d4;
        const float* awp = aw + (size_t)b * 512 + sh * 256 + sq * 64;
        float ax = 0.f, ay = 0.f, az = 0.f, aww = 0.f;
#pragma unroll 8
        for (int ss = 0; ss < 64; ++ss) {
            float wgt = awp[ss];
            float4 e4 = *(const float4*)(eb + (size_t)ss * 1024);
            ax += wgt * e4.x; ay += wgt * e4.y; az += wgt * e4.z; aww += wgt * e4.w;
        }
        __syncthreads();   // racc reuse barrier (phase1 LDS dead)
        racc[sq][dl][0] = ax; racc[sq][dl][1] = ay;
        racc[sq][dl][2] = az; racc[sq][dl][3] = aww;
        __syncthreads();
        if (sq == 0) {
            float r0 = racc[0][dl][0] + racc[1][dl][0] + racc[2][dl][0] + racc[3][dl][0];
            float r1 = racc[0][dl][1] + racc[1][dl][1] + racc[2][dl][1] + racc[3][dl][1];
            float r2 = racc[0][dl][2] + racc[1][dl][2] + racc[2][dl][2] + racc[3][dl][2];
            float r3 = racc[0][dl][3] + racc[1][dl][3] + racc[2][dl][3] + racc[3][dl][3];
            float* cp = cpart + ((size_t)sh * 128 + b) * 1024 + d4;
            *(float4*)cp = (float4){r0, r1, r2, r3};
        }
    }
    __threadfence();
    grid.sync();

    // ---- phase 3: final reduce (blocks 0..127) ----
    if (blk < 128 && t < 256) {
        const int b = blk, d4 = t * 4;
        const float* c0 = cpart + (size_t)b * 1024 + d4;
        const float* c1 = cpart + ((size_t)128 + b) * 1024 + d4;
        float4 a = *(const float4*)c0;
        float4 bb = *(const float4*)c1;
        *(float4*)(ctx + (size_t)b * 1024 + d4) =
            (float4){a.x + bb.x, a.y + bb.y, a.z + bb.z, a.w + bb.w};
    }
}

extern "C" void kernel_launch(void* const* d_in, const int* in_sizes, int n_in,
                              void* d_out, int out_size, void* d_ws, size_t ws_size,
                              hipStream_t stream) {
    const float* hd   = (const float*)d_in[0];
    const float* cd   = (const float*)d_in[1];
    const float* enc  = (const float*)d_in[2];
    const float* mask = (const float*)d_in[3];
    const float* cov  = (const float*)d_in[4];
    const float* Wh   = (const float*)d_in[5];
    const float* Ws   = (const float*)d_in[6];
    const float* Wsb  = (const float*)d_in[7];
    const float* vw   = (const float*)d_in[8];
    const float* wcw  = (const float*)d_in[9];

    float* out  = (float*)d_out;
    float* ctx  = out;
    float* aw   = out + 131072;
    float* ncov = out + 196608;

    // ws layout: p_part 4MB @0 | dec_part 2MB @4M | Wh_bf 2MB @6M | cpart 1MB @8M
    char* ws = (char*)d_ws;
    float* p_part   = (float*)ws;
    float* dec_part = (float*)(ws + (4u << 20));
    short* Wh_bf    = (short*)(ws + (6u << 20));
    float* cpart    = (float*)(ws + (8u << 20));

    prep_kernel<<<1056, 256, 0, stream>>>(Wh, Wh_bf, hd, cd, Ws, dec_part);
    attn_score_gemm7<<<4096, 256, 0, stream>>>(enc, Wh_bf, dec_part, Wsb, cov, wcw, vw, p_part);

    void* args[] = { (void*)&p_part, (void*)&mask, (void*)&cov, (void*)&enc,
                     (void*)&aw, (void*)&ncov, (void*)&ctx, (void*)&cpart };
    hipLaunchCooperativeKernel((void*)post_kernel, dim3(256), dim3(1024), args, 0, stream);
}